// Round 7
// baseline (539.547 us; speedup 1.0000x reference)
//
#include <hip/hip_runtime.h>

// SOM vector-quantizer for MI355X (gfx950).
// Outputs (flat in d_out): [0] loss scalar, [1 .. 8388608] quantized_st
// in [B,C,D,H,W] layout, [8388609 ..] one-hot encodings [N,256].
//
// N = 262144 voxels, EMB_D = 32, K = 256 (16x16 SOM grid).
//
// R6 -> R7: back to the fused R3 skeleton (best so far; both splits lost).
// One change: the distance scan's W delivery. Any VGPR-broadcast path
// (ds_read_b128 or same-address global load) pays 1 KB of register
// writeback per row per wave (~12 cyc) -> 393K cyc/CU = ~164 us, which is
// exactly R3's runtime. Now ONE lane loads each row (16 B writeback) and
// v_readfirstlane broadcasts through SGPRs - the scalar operand of
// v_fmac_f32 is free. Scan becomes VALU-bound (~60 us GPU-wide).
// Bit-exact: rfl returns the loaded bits; fmaf order unchanged (R1-R6:
// absmax 0.0).

#define SOM_K      256
#define EMB_D      32
#define WPAD       36             // LDS row stride (floats): 16B-aligned rows
#define N_VOX      262144
#define SPATIAL    32768          // 32*32*32 per batch
#define OUT_ELEMS  8388608        // 8*32*32768
#define COMMIT_DEN 8388608.0f
#define NSLOT      256            // loss accumulator slots (64B apart)

__device__ __forceinline__ float rfl(float v) {
  return __builtin_bit_cast(
      float, __builtin_amdgcn_readfirstlane(__builtin_bit_cast(int, v)));
}

// ---------------------------------------------------------------------------
// prep: zero the slot accumulators (ws is poisoned to 0xAA every launch).
// Layout: ws[slot*16 + {0,1,2}] = {commit, som, count} partials.
// ---------------------------------------------------------------------------
__global__ __launch_bounds__(256) void som_prep_kernel(float* __restrict__ ws) {
  float4* p = (float4*)ws;               // 256 slots * 16 floats = 1024 float4
  int t = threadIdx.x;
#pragma unroll
  for (int i = 0; i < 4; ++i) p[i * 256 + t] = make_float4(0.f, 0.f, 0.f, 0.f);
}

// ---------------------------------------------------------------------------
// main fused kernel: 1024 blocks x 256 threads, one voxel per thread.
// LDS (38 KB -> 4 blocks/CU) now only for the divergent gathers
// (quantize + neighbors); the scan reads W via lane0-load + readfirstlane.
// ---------------------------------------------------------------------------
__global__ __launch_bounds__(256) void som_main_kernel(
    const float* __restrict__ x,     // [8,32,32,32,32]
    const float* __restrict__ w,     // [256,32]
    float* __restrict__ slots,       // ws: NSLOT x 16 floats
    float* __restrict__ out,         // d_out+1, [8,32,32768]
    float* __restrict__ enc) {       // d_out+1+OUT_ELEMS, [N,256]
  __shared__ __align__(16) float wl[SOM_K * WPAD];
  __shared__ float wsql[SOM_K];      // ||W_k||^2

  const int t = threadIdx.x;

  // Voxel loads first (overlap LDS staging). Coalesced per channel.
  const int n    = blockIdx.x * 256 + t;
  const int base = (n >> 15) * (EMB_D * SPATIAL) + (n & (SPATIAL - 1));
  float xv[EMB_D];
#pragma unroll
  for (int c = 0; c < EMB_D; ++c) xv[c] = x[base + c * SPATIAL];

  // Stage W -> LDS (coalesced read, padded scatter write) for the gathers.
#pragma unroll
  for (int i = 0; i < 32; ++i) {
    int e = i * 256 + t;             // 0..8191
    int r = e >> 5, c = e & 31;
    wl[r * WPAD + c] = w[e];
  }
  // ||W_t||^2, same sequential-fmaf order as the reference-matched R1-R6.
  {
    float s = 0.0f;
#pragma unroll
    for (int c = 0; c < EMB_D; ++c) {
      float v = w[t * EMB_D + c];
      s = fmaf(v, v, s);
    }
    wsql[t] = s;
  }
  __syncthreads();

  float xsq = 0.0f;
#pragma unroll
  for (int c = 0; c < EMB_D; ++c) xsq = fmaf(xv[c], xv[c], xsq);

  // Distance scan over all 256 rows. Lane 0 loads the row (8x float4 under
  // one exec-mask toggle, all 8 loads in flight together); readfirstlane
  // broadcasts each element into an SGPR consumed directly by v_fmac.
  // Exact sequential fmaf order (R1-R6: absmax 0.0); strict '<' = np.argmin.
  const bool is0 = (t & 63) == 0;
  float4 q0 = make_float4(0.f, 0.f, 0.f, 0.f), q1 = q0, q2 = q0, q3 = q0,
         q4 = q0, q5 = q0, q6 = q0, q7 = q0;

  float best = 3.402823466e38f;
  int   bidx = 0;
  for (int k = 0; k < SOM_K; ++k) {
    const float4* row = (const float4*)(w + k * EMB_D);
    if (is0) {
      q0 = row[0]; q1 = row[1]; q2 = row[2]; q3 = row[3];
      q4 = row[4]; q5 = row[5]; q6 = row[6]; q7 = row[7];
    }
    float dot = 0.0f;
    dot = fmaf(rfl(q0.x), xv[0],  dot);
    dot = fmaf(rfl(q0.y), xv[1],  dot);
    dot = fmaf(rfl(q0.z), xv[2],  dot);
    dot = fmaf(rfl(q0.w), xv[3],  dot);
    dot = fmaf(rfl(q1.x), xv[4],  dot);
    dot = fmaf(rfl(q1.y), xv[5],  dot);
    dot = fmaf(rfl(q1.z), xv[6],  dot);
    dot = fmaf(rfl(q1.w), xv[7],  dot);
    dot = fmaf(rfl(q2.x), xv[8],  dot);
    dot = fmaf(rfl(q2.y), xv[9],  dot);
    dot = fmaf(rfl(q2.z), xv[10], dot);
    dot = fmaf(rfl(q2.w), xv[11], dot);
    dot = fmaf(rfl(q3.x), xv[12], dot);
    dot = fmaf(rfl(q3.y), xv[13], dot);
    dot = fmaf(rfl(q3.z), xv[14], dot);
    dot = fmaf(rfl(q3.w), xv[15], dot);
    dot = fmaf(rfl(q4.x), xv[16], dot);
    dot = fmaf(rfl(q4.y), xv[17], dot);
    dot = fmaf(rfl(q4.z), xv[18], dot);
    dot = fmaf(rfl(q4.w), xv[19], dot);
    dot = fmaf(rfl(q5.x), xv[20], dot);
    dot = fmaf(rfl(q5.y), xv[21], dot);
    dot = fmaf(rfl(q5.z), xv[22], dot);
    dot = fmaf(rfl(q5.w), xv[23], dot);
    dot = fmaf(rfl(q6.x), xv[24], dot);
    dot = fmaf(rfl(q6.y), xv[25], dot);
    dot = fmaf(rfl(q6.z), xv[26], dot);
    dot = fmaf(rfl(q6.w), xv[27], dot);
    dot = fmaf(rfl(q7.x), xv[28], dot);
    dot = fmaf(rfl(q7.y), xv[29], dot);
    dot = fmaf(rfl(q7.z), xv[30], dot);
    dot = fmaf(rfl(q7.w), xv[31], dot);
    float d = (xsq + wsql[k]) - 2.0f * dot;   // same rounding order as ref
    if (d < best) { best = d; bidx = k; }
  }

  // One-hot encodings FIRST: start draining the 268 MB write stream early.
  // Wave broadcasts its own 64 BMU indices via v_readlane (no LDS).
  // Coalesced 256B dword stores (enc starts at float offset 1 mod 4).
  {
    const int lane = t & 63, wave = t >> 6;
    float* ep = enc + (size_t)(blockIdx.x * 256 + wave * 64) * SOM_K + lane;
    const int c1 = lane + 64, c2 = lane + 128, c3 = lane + 192;
    for (int row = 0; row < 64; ++row) {
      const int src = __builtin_amdgcn_readlane(bidx, row);  // wave-uniform
      ep[0]   = (lane == src) ? 1.0f : 0.0f;
      ep[64]  = (c1   == src) ? 1.0f : 0.0f;
      ep[128] = (c2   == src) ? 1.0f : 0.0f;
      ep[192] = (c3   == src) ? 1.0f : 0.0f;
      ep += SOM_K;
    }
  }

  // Quantized output + commitment partial (gather row bidx from LDS).
  float commit = 0.0f;
  {
    const float4* qrow = (const float4*)(wl + bidx * WPAD);
#pragma unroll
    for (int j = 0; j < 8; ++j) {
      float4 q = qrow[j];
      float qq[4] = { q.x, q.y, q.z, q.w };
#pragma unroll
      for (int u = 0; u < 4; ++u) {
        int c = 4 * j + u;
        out[base + c * SPATIAL] = qq[u];     // coalesced dword store
        float df = qq[u] - xv[c];
        commit = fmaf(df, df, commit);
      }
    }
  }

  // SOM loss: best (bit-exact scan value) + up/down/left/right neighbors.
  float som = best;
  float cnt = 1.0f;
  {
    const int h  = bidx >> 4;
    const int wc = bidx & 15;
    const int   cand[4]  = { bidx - 16, bidx + 16, bidx - 1, bidx + 1 };
    const float valid[4] = { h > 0 ? 1.f : 0.f,  h < 15 ? 1.f : 0.f,
                             wc > 0 ? 1.f : 0.f, wc < 15 ? 1.f : 0.f };
#pragma unroll
    for (int j = 0; j < 4; ++j) {
      int nk = valid[j] != 0.0f ? cand[j] : bidx;
      const float4* nrow = (const float4*)(wl + nk * WPAD);
      float dot = 0.0f;
#pragma unroll
      for (int jj = 0; jj < 8; ++jj) {
        float4 q = nrow[jj];
        dot = fmaf(q.x, xv[4 * jj + 0], dot);
        dot = fmaf(q.y, xv[4 * jj + 1], dot);
        dot = fmaf(q.z, xv[4 * jj + 2], dot);
        dot = fmaf(q.w, xv[4 * jj + 3], dot);
      }
      float d = (xsq + wsql[nk]) - 2.0f * dot;
      som = fmaf(valid[j], d, som);
      cnt += valid[j];
    }
  }

  // Wave reduction -> 3 atomics per wave into this block's slot (slots 64B
  // apart; 4 waves/slot -> negligible contention).
  for (int off = 32; off > 0; off >>= 1) {
    commit += __shfl_down(commit, off, 64);
    som    += __shfl_down(som,    off, 64);
    cnt    += __shfl_down(cnt,    off, 64);
  }
  if ((t & 63) == 0) {
    float* sp = slots + (size_t)(blockIdx.x & (NSLOT - 1)) * 16;
    atomicAdd(sp + 0, commit);
    atomicAdd(sp + 1, som);
    atomicAdd(sp + 2, cnt);
  }
}

// ---------------------------------------------------------------------------
// final: reduce the 256 slots with one wave, then
// loss = ALPHA * mean(commit) + BETA * som_sum / total_neighbors
// ---------------------------------------------------------------------------
__global__ __launch_bounds__(64) void som_final_kernel(
    const float* __restrict__ slots, float* __restrict__ loss) {
  const int t = threadIdx.x;           // one wave
  float commit = 0.f, som = 0.f, cnt = 0.f;
#pragma unroll
  for (int i = 0; i < 4; ++i) {
    const float* sp = slots + (size_t)(i * 64 + t) * 16;
    commit += sp[0]; som += sp[1]; cnt += sp[2];
  }
  for (int off = 32; off > 0; off >>= 1) {
    commit += __shfl_down(commit, off, 64);
    som    += __shfl_down(som,    off, 64);
    cnt    += __shfl_down(cnt,    off, 64);
  }
  if (t == 0) loss[0] = 6.0f * (commit / COMMIT_DEN) + som / cnt;
}

extern "C" void kernel_launch(void* const* d_in, const int* in_sizes, int n_in,
                              void* d_out, int out_size, void* d_ws, size_t ws_size,
                              hipStream_t stream) {
  const float* x = (const float*)d_in[0];   // [8,32,32,32,32]
  const float* w = (const float*)d_in[1];   // [256,32]
  float* ws  = (float*)d_ws;                // NSLOT x 16 float slots
  float* o   = (float*)d_out;               // [0] loss, then out, then enc

  som_prep_kernel<<<1, 256, 0, stream>>>(ws);
  som_main_kernel<<<N_VOX / 256, 256, 0, stream>>>(
      x, w, ws, o + 1, o + 1 + OUT_ELEMS);
  som_final_kernel<<<1, 64, 0, stream>>>(ws, o);
}

// Round 8
// 513.961 us; speedup vs baseline: 1.0498x; 1.0498x over previous
//
#include <hip/hip_runtime.h>

// SOM vector-quantizer for MI355X (gfx950).
// Outputs (flat in d_out): [0] loss scalar, [1 .. 8388608] quantized_st
// in [B,C,D,H,W] layout, [8388609 ..] one-hot encodings [N,256].
//
// N = 262144 voxels, EMB_D = 32, K = 256 (16x16 SOM grid).
//
// R7 -> R8: revert to the R3 scan (LDS b128 broadcast — best verified).
// Key structural change: the kernel was phase-serialized (scan ~100us with
// memory pipe idle, then 268MB one-hot write storm ~55us with ALUs idle).
// 255/256 of enc is ZEROS, which don't depend on the argmin — so each
// thread zero-fills its own enc row, interleaved INTO the scan k-loop
// (one store per 4 rows). After __syncthreads() (drains vmcnt -> zero
// stores complete), the epilogue writes ONE dword (the 1.0) per thread.
// The enc write phase disappears under the scan.

#define SOM_K      256
#define EMB_D      32
#define WPAD       36             // LDS row stride (floats): 16B-aligned rows
#define N_VOX      262144
#define SPATIAL    32768          // 32*32*32 per batch
#define OUT_ELEMS  8388608        // 8*32*32768
#define COMMIT_DEN 8388608.0f
#define NSLOT      256            // loss accumulator slots (64B apart)

// ---------------------------------------------------------------------------
// prep: zero the slot accumulators (ws is poisoned to 0xAA every launch).
// Layout: ws[slot*16 + {0,1,2}] = {commit, som, count} partials.
// ---------------------------------------------------------------------------
__global__ __launch_bounds__(256) void som_prep_kernel(float* __restrict__ ws) {
  float4* p = (float4*)ws;               // 256 slots * 16 floats = 1024 float4
  int t = threadIdx.x;
#pragma unroll
  for (int i = 0; i < 4; ++i) p[i * 256 + t] = make_float4(0.f, 0.f, 0.f, 0.f);
}

// ---------------------------------------------------------------------------
// main fused kernel: 1024 blocks x 256 threads, one voxel per thread.
// LDS: codebook padded to 36-float rows (16B-aligned b128 broadcast reads)
// + per-row ||W||^2. 4 blocks/CU.
// ---------------------------------------------------------------------------
__global__ __launch_bounds__(256) void som_main_kernel(
    const float* __restrict__ x,     // [8,32,32,32,32]
    const float* __restrict__ w,     // [256,32]
    float* __restrict__ slots,       // ws: NSLOT x 16 floats
    float* __restrict__ out,         // d_out+1, [8,32,32768]
    float* __restrict__ enc) {       // d_out+1+OUT_ELEMS, [N,256]
  __shared__ __align__(16) float wl[SOM_K * WPAD];
  __shared__ float wsql[SOM_K];      // ||W_k||^2

  const int t = threadIdx.x;

  // Voxel loads first (overlap LDS staging). Coalesced per channel.
  const int n    = blockIdx.x * 256 + t;
  const int base = (n >> 15) * (EMB_D * SPATIAL) + (n & (SPATIAL - 1));
  float xv[EMB_D];
#pragma unroll
  for (int c = 0; c < EMB_D; ++c) xv[c] = x[base + c * SPATIAL];

  // Stage W -> LDS (coalesced read, padded scatter write).
#pragma unroll
  for (int i = 0; i < 32; ++i) {
    int e = i * 256 + t;             // 0..8191
    int r = e >> 5, c = e & 31;
    wl[r * WPAD + c] = w[e];
  }
  // ||W_t||^2, same sequential-fmaf order as the reference-matched R1-R7.
  {
    float s = 0.0f;
#pragma unroll
    for (int c = 0; c < EMB_D; ++c) {
      float v = w[t * EMB_D + c];
      s = fmaf(v, v, s);
    }
    wsql[t] = s;
  }
  __syncthreads();

  float xsq = 0.0f;
#pragma unroll
  for (int c = 0; c < EMB_D; ++c) xsq = fmaf(xv[c], xv[c], xsq);

  // This thread's enc row [n*256, (n+1)*256). Row byte base == 4 mod 16
  // (d_out 256B-aligned, +1 float header, +n*1KB), so rowp+3 is 16B-aligned:
  // 63 float4 stores cover cols 3..254; dwords cover 0,1,2,255.
  float* rowp = enc + (size_t)n * SOM_K;
  float4* zp  = (float4*)(rowp + 3);
  const float4 z4 = make_float4(0.f, 0.f, 0.f, 0.f);

  // Distance scan over all 256 rows via same-address float4 broadcast
  // (exact sequential fmaf order, R1-R7: absmax 0.0; strict '<' =
  // np.argmin), with one independent enc-zero store interleaved per 4 rows
  // so the 268 MB write stream drains UNDER the scan compute.
  float best = 3.402823466e38f;
  int   bidx = 0;
#pragma unroll 4
  for (int k = 0; k < SOM_K; ++k) {
    const float4* row = (const float4*)(wl + k * WPAD);
    float dot = 0.0f;
#pragma unroll
    for (int j = 0; j < 8; ++j) {
      float4 q = row[j];
      dot = fmaf(q.x, xv[4 * j + 0], dot);
      dot = fmaf(q.y, xv[4 * j + 1], dot);
      dot = fmaf(q.z, xv[4 * j + 2], dot);
      dot = fmaf(q.w, xv[4 * j + 3], dot);
    }
    float d = (xsq + wsql[k]) - 2.0f * dot;   // same rounding order as ref
    if (d < best) { best = d; bidx = k; }

    if ((k & 3) == 0) {
      const int z = k >> 2;                   // 0..63
      if (z < 63) {
        zp[z] = z4;                           // cols 3+4z .. 6+4z
      } else {
        rowp[0] = 0.f; rowp[1] = 0.f; rowp[2] = 0.f; rowp[255] = 0.f;
      }
    }
  }

  // Barrier drains vmcnt (compiler emits s_waitcnt vmcnt(0) before
  // s_barrier) -> all zero stores complete before the 1.0 store below.
  __syncthreads();

  // The single nonzero of this thread's one-hot row.
  rowp[bidx] = 1.0f;

  // Quantized output + commitment partial (gather row bidx from LDS).
  float commit = 0.0f;
  {
    const float4* qrow = (const float4*)(wl + bidx * WPAD);
#pragma unroll
    for (int j = 0; j < 8; ++j) {
      float4 q = qrow[j];
      float qq[4] = { q.x, q.y, q.z, q.w };
#pragma unroll
      for (int u = 0; u < 4; ++u) {
        int c = 4 * j + u;
        out[base + c * SPATIAL] = qq[u];     // coalesced dword store
        float df = qq[u] - xv[c];
        commit = fmaf(df, df, commit);
      }
    }
  }

  // SOM loss: best (bit-exact scan value) + up/down/left/right neighbors.
  float som = best;
  float cnt = 1.0f;
  {
    const int h  = bidx >> 4;
    const int wc = bidx & 15;
    const int   cand[4]  = { bidx - 16, bidx + 16, bidx - 1, bidx + 1 };
    const float valid[4] = { h > 0 ? 1.f : 0.f,  h < 15 ? 1.f : 0.f,
                             wc > 0 ? 1.f : 0.f, wc < 15 ? 1.f : 0.f };
#pragma unroll
    for (int j = 0; j < 4; ++j) {
      int nk = valid[j] != 0.0f ? cand[j] : bidx;
      const float4* nrow = (const float4*)(wl + nk * WPAD);
      float dot = 0.0f;
#pragma unroll
      for (int jj = 0; jj < 8; ++jj) {
        float4 q = nrow[jj];
        dot = fmaf(q.x, xv[4 * jj + 0], dot);
        dot = fmaf(q.y, xv[4 * jj + 1], dot);
        dot = fmaf(q.z, xv[4 * jj + 2], dot);
        dot = fmaf(q.w, xv[4 * jj + 3], dot);
      }
      float d = (xsq + wsql[nk]) - 2.0f * dot;
      som = fmaf(valid[j], d, som);
      cnt += valid[j];
    }
  }

  // Wave reduction -> 3 atomics per wave into this block's slot (slots 64B
  // apart; 4 waves/slot -> negligible contention).
  for (int off = 32; off > 0; off >>= 1) {
    commit += __shfl_down(commit, off, 64);
    som    += __shfl_down(som,    off, 64);
    cnt    += __shfl_down(cnt,    off, 64);
  }
  if ((t & 63) == 0) {
    float* sp = slots + (size_t)(blockIdx.x & (NSLOT - 1)) * 16;
    atomicAdd(sp + 0, commit);
    atomicAdd(sp + 1, som);
    atomicAdd(sp + 2, cnt);
  }
}

// ---------------------------------------------------------------------------
// final: reduce the 256 slots with one wave, then
// loss = ALPHA * mean(commit) + BETA * som_sum / total_neighbors
// ---------------------------------------------------------------------------
__global__ __launch_bounds__(64) void som_final_kernel(
    const float* __restrict__ slots, float* __restrict__ loss) {
  const int t = threadIdx.x;           // one wave
  float commit = 0.f, som = 0.f, cnt = 0.f;
#pragma unroll
  for (int i = 0; i < 4; ++i) {
    const float* sp = slots + (size_t)(i * 64 + t) * 16;
    commit += sp[0]; som += sp[1]; cnt += sp[2];
  }
  for (int off = 32; off > 0; off >>= 1) {
    commit += __shfl_down(commit, off, 64);
    som    += __shfl_down(som,    off, 64);
    cnt    += __shfl_down(cnt,    off, 64);
  }
  if (t == 0) loss[0] = 6.0f * (commit / COMMIT_DEN) + som / cnt;
}

extern "C" void kernel_launch(void* const* d_in, const int* in_sizes, int n_in,
                              void* d_out, int out_size, void* d_ws, size_t ws_size,
                              hipStream_t stream) {
  const float* x = (const float*)d_in[0];   // [8,32,32,32,32]
  const float* w = (const float*)d_in[1];   // [256,32]
  float* ws  = (float*)d_ws;                // NSLOT x 16 float slots
  float* o   = (float*)d_out;               // [0] loss, then out, then enc

  som_prep_kernel<<<1, 256, 0, stream>>>(ws);
  som_main_kernel<<<N_VOX / 256, 256, 0, stream>>>(
      x, w, ws, o + 1, o + 1 + OUT_ELEMS);
  som_final_kernel<<<1, 64, 0, stream>>>(ws, o);
}